// Round 1
// baseline (448.719 us; speedup 1.0000x reference)
//
#include <hip/hip_runtime.h>
#include <stdint.h>
#include <math.h>

#define DEV static __device__ __forceinline__

typedef __attribute__((ext_vector_type(8))) short bf16x8;
typedef __attribute__((ext_vector_type(4))) float f32x4;
typedef __attribute__((ext_vector_type(8))) unsigned short u16x8;
typedef __attribute__((ext_vector_type(4))) unsigned short u16x4;

enum { B_ = 2, S_ = 2048, D_ = 2048, H_ = 32, HD_ = 64, N3_ = 6144, M_ = 4096 };

DEV unsigned short f2bf(float f) {
  unsigned u = __float_as_uint(f);
  u += 0x7FFFu + ((u >> 16) & 1u);
  return (unsigned short)(u >> 16);
}
DEV float bf2f(unsigned short s) { return __uint_as_float(((unsigned)s) << 16); }

DEV void load16(const void* g, void* l) {
  __builtin_amdgcn_global_load_lds((const __attribute__((address_space(1))) void*)g,
                                   (__attribute__((address_space(3))) void*)l,
                                   16, 0, 0);
}

DEV f32x4 mfma16(bf16x8 a, bf16x8 b, f32x4 c) {
  return __builtin_amdgcn_mfma_f32_16x16x32_bf16(a, b, c, 0, 0, 0);
}

// ---------------------------------------------------------------- cvt f32->bf16
__global__ __launch_bounds__(256) void cvt_bf16(const float* __restrict__ in,
                                                unsigned short* __restrict__ out, int n) {
  int i = blockIdx.x * 256 + threadIdx.x;
  if (i * 8 >= n) return;
  const float4* in4 = (const float4*)in;
  float4 a = in4[i * 2 + 0];
  float4 b = in4[i * 2 + 1];
  u16x8 o;
  o[0] = f2bf(a.x); o[1] = f2bf(a.y); o[2] = f2bf(a.z); o[3] = f2bf(a.w);
  o[4] = f2bf(b.x); o[5] = f2bf(b.y); o[6] = f2bf(b.z); o[7] = f2bf(b.w);
  *(u16x8*)(out + (size_t)i * 8) = o;
}

// ------------------------------------------- transpose f32 [K][N] -> bf16 [N][K]
__global__ __launch_bounds__(256) void transpose_bf16(const float* __restrict__ W,
                                                      unsigned short* __restrict__ Wt,
                                                      int Kg, int Ng) {
  __shared__ float tile[32][33];
  const int tn = blockIdx.x, tk = blockIdx.y;
  const int t = threadIdx.x;
  const int r = t >> 3, c4 = (t & 7) * 4;
  float4 v = *(const float4*)(W + (size_t)(tk * 32 + r) * Ng + tn * 32 + c4);
  tile[r][c4 + 0] = v.x; tile[r][c4 + 1] = v.y;
  tile[r][c4 + 2] = v.z; tile[r][c4 + 3] = v.w;
  __syncthreads();
  u16x4 o;
  o[0] = f2bf(tile[c4 + 0][r]);
  o[1] = f2bf(tile[c4 + 1][r]);
  o[2] = f2bf(tile[c4 + 2][r]);
  o[3] = f2bf(tile[c4 + 3][r]);
  *(u16x4*)(Wt + (size_t)(tn * 32 + r) * Kg + tk * 32 + c4) = o;
}

// ------------------------------------------------------------- GEMM C = A @ B^T
// A: [Mg][Kg] bf16 row-major.  BT: [Ng][Kg] bf16 row-major.  128x128 tile, BK=32.
DEV int xsw(int row) { return (row ^ (row >> 2)) & 3; }

template <int OUT_BF16>
__global__ __launch_bounds__(256) void gemm_bt(const unsigned short* __restrict__ A,
                                               const unsigned short* __restrict__ BT,
                                               const float* __restrict__ bias,
                                               void* __restrict__ Cout,
                                               int Mg, int Ng, int Kg) {
  __shared__ __align__(16) unsigned short lA[128 * 32];
  __shared__ __align__(16) unsigned short lB[128 * 32];
  const int tid = threadIdx.x;
  const int lane = tid & 63, wv = tid >> 6;
  const int g = lane >> 4, l16 = lane & 15;
  const int wr = wv >> 1, wc = wv & 1;
  const int rb = blockIdx.x * 128, cb = blockIdx.y * 128;

  f32x4 acc[4][4] = {};

  for (int k0 = 0; k0 < Kg; k0 += 32) {
    __syncthreads();
#pragma unroll
    for (int c = 0; c < 2; ++c) {
      int p = c * 256 + tid;
      int row = p >> 2;
      int k8l = (p & 3) ^ xsw(row);
      load16(A + (size_t)(rb + row) * Kg + k0 + 8 * k8l, (char*)lA + p * 16);
      load16(BT + (size_t)(cb + row) * Kg + k0 + 8 * k8l, (char*)lB + p * 16);
    }
    __syncthreads();
    bf16x8 af[4], bfr[4];
#pragma unroll
    for (int m = 0; m < 4; ++m) {
      int row = wr * 64 + m * 16 + l16;
      af[m] = *(const bf16x8*)((const char*)lA + (size_t)(row * 4 + (g ^ xsw(row))) * 16);
    }
#pragma unroll
    for (int n = 0; n < 4; ++n) {
      int row = wc * 64 + n * 16 + l16;
      bfr[n] = *(const bf16x8*)((const char*)lB + (size_t)(row * 4 + (g ^ xsw(row))) * 16);
    }
#pragma unroll
    for (int m = 0; m < 4; ++m)
#pragma unroll
      for (int n = 0; n < 4; ++n)
        acc[m][n] = mfma16(af[m], bfr[n], acc[m][n]);
  }

#pragma unroll
  for (int m = 0; m < 4; ++m)
#pragma unroll
    for (int n = 0; n < 4; ++n)
#pragma unroll
      for (int r = 0; r < 4; ++r) {
        int row = rb + wr * 64 + m * 16 + g * 4 + r;
        int col = cb + wc * 64 + n * 16 + l16;
        float v = acc[m][n][r] + bias[col];
        if (OUT_BF16)
          ((unsigned short*)Cout)[(size_t)row * Ng + col] = f2bf(v);
        else
          ((float*)Cout)[(size_t)row * Ng + col] = v;
      }
}

// -------------------------------------------------------------- RoPE (in place)
__global__ __launch_bounds__(256) void rope_kernel(unsigned short* __restrict__ qkv) {
  const int idx = blockIdx.x * 256 + threadIdx.x;  // (b, s, h)
  const int h = idx & 31;
  const int s = (idx >> 5) & (S_ - 1);
  const int b = idx >> 16;
  float cs[16], sn[16];
#pragma unroll
  for (int j = 0; j < 16; ++j) {
    float inv = exp2f(-(float)j * 0.83048202372184056f);  // log2(10000)/16
    float fr = (float)s * inv;
    sincosf(fr, &sn[j], &cs[j]);
  }
  size_t base = (size_t)(b * S_ + s) * N3_ + h * 64;
#pragma unroll
  for (int part = 0; part < 2; ++part) {  // q then k
    unsigned short* p = qkv + base + part * 2048;
    u16x8 u0 = *(u16x8*)(p + 0), u1 = *(u16x8*)(p + 8);
    u16x8 u2 = *(u16x8*)(p + 16), u3 = *(u16x8*)(p + 24);
    float a1[16], a2[16];
#pragma unroll
    for (int j = 0; j < 8; ++j) {
      a1[j] = bf2f(u0[j]); a1[j + 8] = bf2f(u1[j]);
      a2[j] = bf2f(u2[j]); a2[j + 8] = bf2f(u3[j]);
    }
    u16x8 r0, r1, r2, r3;
#pragma unroll
    for (int j = 0; j < 8; ++j) {
      r0[j] = f2bf(a1[j] * cs[j] - a2[j] * sn[j]);
      r2[j] = f2bf(a1[j] * sn[j] + a2[j] * cs[j]);
      r1[j] = f2bf(a1[j + 8] * cs[j + 8] - a2[j + 8] * sn[j + 8]);
      r3[j] = f2bf(a1[j + 8] * sn[j + 8] + a2[j + 8] * cs[j + 8]);
    }
    *(u16x8*)(p + 0) = r0;  *(u16x8*)(p + 8) = r1;
    *(u16x8*)(p + 16) = r2; *(u16x8*)(p + 24) = r3;
  }
}

// ------------------------------------------------- V transpose -> [B,H,64,S]
__global__ __launch_bounds__(256) void vtrans(const unsigned short* __restrict__ qkv,
                                              unsigned short* __restrict__ vt) {
  __shared__ unsigned short tile[64][72];
  const int s0 = blockIdx.x * 64;
  const int bh = blockIdx.y;
  const int b = bh >> 5, h = bh & 31;
  const int t = threadIdx.x;
#pragma unroll
  for (int c = 0; c < 2; ++c) {
    int sl = (c * 256 + t) >> 3, d8 = t & 7;
    u16x8 v = *(const u16x8*)(qkv + (size_t)(b * S_ + s0 + sl) * N3_ + 4096 + h * 64 + d8 * 8);
    *(u16x8*)(&tile[sl][d8 * 8]) = v;
  }
  __syncthreads();
#pragma unroll
  for (int c = 0; c < 2; ++c) {
    int dl = (c * 256 + t) >> 3, s8 = t & 7;
    u16x8 o;
#pragma unroll
    for (int j = 0; j < 8; ++j) o[j] = tile[s8 * 8 + j][dl];
    *(u16x8*)(vt + (size_t)(bh * 64 + dl) * S_ + s0 + s8 * 8) = o;
  }
}

// ----------------------------------------------------------- flash attention
// qkv: [B,S,3*2048] bf16 (q roped, k roped).  vt: [B*H, 64, S] bf16.
// ao: [B*S, 2048] bf16.
__global__ __launch_bounds__(256, 2) void attn_kernel(const unsigned short* __restrict__ qkv,
                                                      const unsigned short* __restrict__ vt,
                                                      unsigned short* __restrict__ ao) {
  __shared__ __align__(16) unsigned char lds[32768];  // K 8K | Vt 8K | P 4x4K
  const int tid = threadIdx.x;
  const int lane = tid & 63, wv = tid >> 6;
  const int g = lane >> 4, l16 = lane & 15;
  const int qi = blockIdx.x;           // 16 q-blocks of 128
  const int bh = blockIdx.y;           // 64
  const int b = bh >> 5, h = bh & 31;
  const int qbase = qi * 128;
  const int srow0 = qbase + wv * 32;

  bf16x8 qf[2][2];
#pragma unroll
  for (int m = 0; m < 2; ++m)
#pragma unroll
    for (int kt = 0; kt < 2; ++kt) {
      int s = srow0 + m * 16 + l16;
      qf[m][kt] = *(const bf16x8*)(qkv + (size_t)(b * S_ + s) * N3_ + h * 64 + kt * 32 + g * 8);
    }

  float mrun[2][4], lrun[2][4];
#pragma unroll
  for (int m = 0; m < 2; ++m)
#pragma unroll
    for (int r = 0; r < 4; ++r) { mrun[m][r] = -INFINITY; lrun[m][r] = 0.f; }
  f32x4 o[2][4] = {};

  unsigned char* pl = lds + 16384 + wv * 4096;
  const int nkv = (qbase + 128) >> 6;
  for (int kb = 0; kb < nkv; ++kb) {
    const int kvb = kb << 6;
#pragma unroll
    for (int c = 0; c < 2; ++c) {
      int p = c * 256 + tid;
      int row = p >> 3, k8 = (p & 7) ^ (row & 7);
      load16(qkv + (size_t)(b * S_ + kvb + row) * N3_ + 2048 + h * 64 + 8 * k8, lds + p * 16);
      load16(vt + (size_t)(bh * 64 + row) * S_ + kvb + 8 * k8, lds + 8192 + p * 16);
    }
    __syncthreads();

    // ---- QK^T
    f32x4 sc[2][4];
#pragma unroll
    for (int n = 0; n < 4; ++n) {
      int row = n * 16 + l16;
      bf16x8 kf0 = *(const bf16x8*)(lds + (row * 8 + ((g + 0) ^ (row & 7))) * 16);
      bf16x8 kf1 = *(const bf16x8*)(lds + (row * 8 + ((g + 4) ^ (row & 7))) * 16);
#pragma unroll
      for (int m = 0; m < 2; ++m) {
        f32x4 z = {};
        z = mfma16(qf[m][0], kf0, z);
        z = mfma16(qf[m][1], kf1, z);
        sc[m][n] = z;
      }
    }

    // ---- online softmax (per (m,reg) row; lanes of a 16-group share a row)
#pragma unroll
    for (int m = 0; m < 2; ++m)
#pragma unroll
      for (int r = 0; r < 4; ++r) {
        const int rowg = srow0 + m * 16 + g * 4 + r;
#pragma unroll
        for (int n = 0; n < 4; ++n) {
          float v = sc[m][n][r] * 0.125f;
          int col = kvb + n * 16 + l16;
          sc[m][n][r] = (col > rowg) ? -INFINITY : v;
        }
        float mx = fmaxf(fmaxf(sc[m][0][r], sc[m][1][r]), fmaxf(sc[m][2][r], sc[m][3][r]));
#pragma unroll
        for (int off = 1; off < 16; off <<= 1) mx = fmaxf(mx, __shfl_xor(mx, off, 64));
        float mn = fmaxf(mrun[m][r], mx);
        float alpha = __expf(mrun[m][r] - mn);
        float rs = 0.f;
        const int prow = m * 16 + g * 4 + r;
#pragma unroll
        for (int n = 0; n < 4; ++n) {
          float p = __expf(sc[m][n][r] - mn);
          rs += p;
          int pcol = n * 16 + l16;
          int unit = prow * 8 + ((pcol >> 3) ^ (prow & 7));
          *(unsigned short*)(pl + unit * 16 + (pcol & 7) * 2) = f2bf(p);
        }
#pragma unroll
        for (int off = 1; off < 16; off <<= 1) rs += __shfl_xor(rs, off, 64);
        lrun[m][r] = lrun[m][r] * alpha + rs;
        mrun[m][r] = mn;
#pragma unroll
        for (int d = 0; d < 4; ++d) o[m][d][r] *= alpha;
      }

    // ---- P @ V
    bf16x8 pf[2][2];
#pragma unroll
    for (int m = 0; m < 2; ++m)
#pragma unroll
      for (int kt = 0; kt < 2; ++kt) {
        int row = m * 16 + l16;
        pf[m][kt] = *(const bf16x8*)(pl + (row * 8 + ((g + 4 * kt) ^ (row & 7))) * 16);
      }
#pragma unroll
    for (int d = 0; d < 4; ++d) {
      int row = d * 16 + l16;
      bf16x8 vf0 = *(const bf16x8*)(lds + 8192 + (row * 8 + ((g + 0) ^ (row & 7))) * 16);
      bf16x8 vf1 = *(const bf16x8*)(lds + 8192 + (row * 8 + ((g + 4) ^ (row & 7))) * 16);
#pragma unroll
      for (int m = 0; m < 2; ++m) {
        o[m][d] = mfma16(pf[m][0], vf0, o[m][d]);
        o[m][d] = mfma16(pf[m][1], vf1, o[m][d]);
      }
    }
    __syncthreads();
  }

#pragma unroll
  for (int m = 0; m < 2; ++m)
#pragma unroll
    for (int r = 0; r < 4; ++r) {
      float inv = 1.0f / lrun[m][r];
      int s = srow0 + m * 16 + g * 4 + r;
#pragma unroll
      for (int d = 0; d < 4; ++d) {
        int col = h * 64 + d * 16 + l16;
        ao[(size_t)(b * S_ + s) * D_ + col] = f2bf(o[m][d][r] * inv);
      }
    }
}

// ---------------------------------------------------------------------- launch
extern "C" void kernel_launch(void* const* d_in, const int* in_sizes, int n_in,
                              void* d_out, int out_size, void* d_ws, size_t ws_size,
                              hipStream_t stream) {
  const float* x = (const float*)d_in[0];
  const float* Wqkv = (const float*)d_in[1];
  const float* bqkv = (const float*)d_in[2];
  const float* Wout = (const float*)d_in[3];
  const float* bout = (const float*)d_in[4];
  float* out = (float*)d_out;

  char* ws = (char*)d_ws;
  unsigned short* Xb = (unsigned short*)(ws + 0);                  // 16 MiB (reused as AO)
  unsigned short* Wqkvt = (unsigned short*)(ws + 16777216);        // 24 MiB
  unsigned short* Woutt = (unsigned short*)(ws + 41943040);        // 8 MiB
  unsigned short* QKVb = (unsigned short*)(ws + 50331648);         // 48 MiB
  unsigned short* Vt = (unsigned short*)(ws + 100663296);          // 16 MiB
  unsigned short* AO = Xb;  // Xb is dead after gemm1

  cvt_bf16<<<4096, 256, 0, stream>>>(x, Xb, M_ * D_);
  transpose_bf16<<<dim3(192, 64), 256, 0, stream>>>(Wqkv, Wqkvt, 2048, 6144);
  transpose_bf16<<<dim3(64, 64), 256, 0, stream>>>(Wout, Woutt, 2048, 2048);
  gemm_bt<1><<<dim3(32, 48), 256, 0, stream>>>(Xb, Wqkvt, bqkv, QKVb, M_, N3_, D_);
  rope_kernel<<<512, 256, 0, stream>>>(QKVb);
  vtrans<<<dim3(32, 64), 256, 0, stream>>>(QKVb, Vt);
  attn_kernel<<<dim3(16, 64), 256, 0, stream>>>(QKVb, Vt, AO);
  gemm_bt<0><<<dim3(32, 16), 256, 0, stream>>>(AO, Woutt, bout, out, M_, D_, D_);
}

// Round 2
// 306.828 us; speedup vs baseline: 1.4624x; 1.4624x over previous
//
#include <hip/hip_runtime.h>
#include <stdint.h>
#include <math.h>

#define DEV static __device__ __forceinline__

typedef __attribute__((ext_vector_type(8))) short bf16x8;
typedef __attribute__((ext_vector_type(4))) float f32x4;
typedef __attribute__((ext_vector_type(8))) unsigned short u16x8;
typedef __attribute__((ext_vector_type(4))) unsigned short u16x4;
typedef __attribute__((ext_vector_type(2))) unsigned int u32x2;

enum { B_ = 2, S_ = 2048, D_ = 2048, H_ = 32, HD_ = 64, N3_ = 6144, M_ = 4096 };

DEV unsigned short f2bf(float f) {
  unsigned u = __float_as_uint(f);
  u += 0x7FFFu + ((u >> 16) & 1u);
  return (unsigned short)(u >> 16);
}
DEV float bf2f(unsigned short s) { return __uint_as_float(((unsigned)s) << 16); }

DEV void load16(const void* g, void* l) {
  __builtin_amdgcn_global_load_lds((const __attribute__((address_space(1))) void*)g,
                                   (__attribute__((address_space(3))) void*)l,
                                   16, 0, 0);
}

DEV f32x4 mfma16(bf16x8 a, bf16x8 b, f32x4 c) {
  return __builtin_amdgcn_mfma_f32_16x16x32_bf16(a, b, c, 0, 0, 0);
}

// ---------------------------------------------------------------- cvt f32->bf16
__global__ __launch_bounds__(256) void cvt_bf16(const float* __restrict__ in,
                                                unsigned short* __restrict__ out, int n) {
  int i = blockIdx.x * 256 + threadIdx.x;
  if (i * 8 >= n) return;
  const float4* in4 = (const float4*)in;
  float4 a = in4[i * 2 + 0];
  float4 b = in4[i * 2 + 1];
  u16x8 o;
  o[0] = f2bf(a.x); o[1] = f2bf(a.y); o[2] = f2bf(a.z); o[3] = f2bf(a.w);
  o[4] = f2bf(b.x); o[5] = f2bf(b.y); o[6] = f2bf(b.z); o[7] = f2bf(b.w);
  *(u16x8*)(out + (size_t)i * 8) = o;
}

// ------------------------------------------- transpose f32 [K][N] -> bf16 [N][K]
__global__ __launch_bounds__(256) void transpose_bf16(const float* __restrict__ W,
                                                      unsigned short* __restrict__ Wt,
                                                      int Kg, int Ng) {
  __shared__ float tile[32][33];
  const int tn = blockIdx.x, tk = blockIdx.y;
  const int t = threadIdx.x;
  const int r = t >> 3, c4 = (t & 7) * 4;
  float4 v = *(const float4*)(W + (size_t)(tk * 32 + r) * Ng + tn * 32 + c4);
  tile[r][c4 + 0] = v.x; tile[r][c4 + 1] = v.y;
  tile[r][c4 + 2] = v.z; tile[r][c4 + 3] = v.w;
  __syncthreads();
  u16x4 o;
  o[0] = f2bf(tile[c4 + 0][r]);
  o[1] = f2bf(tile[c4 + 1][r]);
  o[2] = f2bf(tile[c4 + 2][r]);
  o[3] = f2bf(tile[c4 + 3][r]);
  *(u16x4*)(Wt + (size_t)(tn * 32 + r) * Kg + tk * 32 + c4) = o;
}

// ------------------------------------------------------------- GEMM C = A @ B^T
DEV int xsw(int row) { return (row ^ (row >> 2)) & 3; }

template <int OUT_BF16>
__global__ __launch_bounds__(256) void gemm_bt(const unsigned short* __restrict__ A,
                                               const unsigned short* __restrict__ BT,
                                               const float* __restrict__ bias,
                                               void* __restrict__ Cout,
                                               int Mg, int Ng, int Kg) {
  __shared__ __align__(16) unsigned short lA[128 * 32];
  __shared__ __align__(16) unsigned short lB[128 * 32];
  const int tid = threadIdx.x;
  const int lane = tid & 63, wv = tid >> 6;
  const int g = lane >> 4, l16 = lane & 15;
  const int wr = wv >> 1, wc = wv & 1;
  const int rb = blockIdx.x * 128, cb = blockIdx.y * 128;

  f32x4 acc[4][4] = {};

  for (int k0 = 0; k0 < Kg; k0 += 32) {
    __syncthreads();
#pragma unroll
    for (int c = 0; c < 2; ++c) {
      int p = c * 256 + tid;
      int row = p >> 2;
      int k8l = (p & 3) ^ xsw(row);
      load16(A + (size_t)(rb + row) * Kg + k0 + 8 * k8l, (char*)lA + p * 16);
      load16(BT + (size_t)(cb + row) * Kg + k0 + 8 * k8l, (char*)lB + p * 16);
    }
    __syncthreads();
    bf16x8 af[4], bfr[4];
#pragma unroll
    for (int m = 0; m < 4; ++m) {
      int row = wr * 64 + m * 16 + l16;
      af[m] = *(const bf16x8*)((const char*)lA + (size_t)(row * 4 + (g ^ xsw(row))) * 16);
    }
#pragma unroll
    for (int n = 0; n < 4; ++n) {
      int row = wc * 64 + n * 16 + l16;
      bfr[n] = *(const bf16x8*)((const char*)lB + (size_t)(row * 4 + (g ^ xsw(row))) * 16);
    }
#pragma unroll
    for (int m = 0; m < 4; ++m)
#pragma unroll
      for (int n = 0; n < 4; ++n)
        acc[m][n] = mfma16(af[m], bfr[n], acc[m][n]);
  }

#pragma unroll
  for (int m = 0; m < 4; ++m)
#pragma unroll
    for (int n = 0; n < 4; ++n)
#pragma unroll
      for (int r = 0; r < 4; ++r) {
        int row = rb + wr * 64 + m * 16 + g * 4 + r;
        int col = cb + wc * 64 + n * 16 + l16;
        float v = acc[m][n][r] + bias[col];
        if (OUT_BF16)
          ((unsigned short*)Cout)[(size_t)row * Ng + col] = f2bf(v);
        else
          ((float*)Cout)[(size_t)row * Ng + col] = v;
      }
}

// -------------------------------------------------------------- RoPE (in place)
__global__ __launch_bounds__(256) void rope_kernel(unsigned short* __restrict__ qkv) {
  const int idx = blockIdx.x * 256 + threadIdx.x;  // (b, s, h)
  const int h = idx & 31;
  const int s = (idx >> 5) & (S_ - 1);
  const int b = idx >> 16;
  float cs[16], sn[16];
#pragma unroll
  for (int j = 0; j < 16; ++j) {
    float inv = exp2f(-(float)j * 0.83048202372184056f);  // log2(10000)/16
    float fr = (float)s * inv;
    sincosf(fr, &sn[j], &cs[j]);
  }
  size_t base = (size_t)(b * S_ + s) * N3_ + h * 64;
#pragma unroll
  for (int part = 0; part < 2; ++part) {  // q then k
    unsigned short* p = qkv + base + part * 2048;
    u16x8 u0 = *(u16x8*)(p + 0), u1 = *(u16x8*)(p + 8);
    u16x8 u2 = *(u16x8*)(p + 16), u3 = *(u16x8*)(p + 24);
    float a1[16], a2[16];
#pragma unroll
    for (int j = 0; j < 8; ++j) {
      a1[j] = bf2f(u0[j]); a1[j + 8] = bf2f(u1[j]);
      a2[j] = bf2f(u2[j]); a2[j + 8] = bf2f(u3[j]);
    }
    u16x8 r0, r1, r2, r3;
#pragma unroll
    for (int j = 0; j < 8; ++j) {
      r0[j] = f2bf(a1[j] * cs[j] - a2[j] * sn[j]);
      r2[j] = f2bf(a1[j] * sn[j] + a2[j] * cs[j]);
      r1[j] = f2bf(a1[j + 8] * cs[j + 8] - a2[j + 8] * sn[j + 8]);
      r3[j] = f2bf(a1[j + 8] * sn[j + 8] + a2[j + 8] * cs[j + 8]);
    }
    *(u16x8*)(p + 0) = r0;  *(u16x8*)(p + 8) = r1;
    *(u16x8*)(p + 16) = r2; *(u16x8*)(p + 24) = r3;
  }
}

// ------------------------------------------------- V transpose -> [B,H,64,S]
__global__ __launch_bounds__(256) void vtrans(const unsigned short* __restrict__ qkv,
                                              unsigned short* __restrict__ vt) {
  __shared__ unsigned short tile[64][72];
  const int s0 = blockIdx.x * 64;
  const int bh = blockIdx.y;
  const int b = bh >> 5, h = bh & 31;
  const int t = threadIdx.x;
#pragma unroll
  for (int c = 0; c < 2; ++c) {
    int sl = (c * 256 + t) >> 3, d8 = t & 7;
    u16x8 v = *(const u16x8*)(qkv + (size_t)(b * S_ + s0 + sl) * N3_ + 4096 + h * 64 + d8 * 8);
    *(u16x8*)(&tile[sl][d8 * 8]) = v;
  }
  __syncthreads();
#pragma unroll
  for (int c = 0; c < 2; ++c) {
    int dl = (c * 256 + t) >> 3, s8 = t & 7;
    u16x8 o;
#pragma unroll
    for (int j = 0; j < 8; ++j) o[j] = tile[s8 * 8 + j][dl];
    *(u16x8*)(vt + (size_t)(bh * 64 + dl) * S_ + s0 + s8 * 8) = o;
  }
}

// ----------------------------------------------------------- flash attention
// Swapped-operand layout: lane l16 = q-row for softmax AND O accumulation.
// LDS: K dbuf 2x8K | V dbuf 2x8K | P 4 waves x 4K = 48KB.
DEV void stage_kv(const unsigned short* __restrict__ qkv,
                  const unsigned short* __restrict__ vt,
                  unsigned char* lds, int bS, int bh64, int hoff, int kvb, int buf, int tid) {
#pragma unroll
  for (int c = 0; c < 2; ++c) {
    int p = c * 256 + tid;
    int row = p >> 3, k8 = (p & 7) ^ (row & 7);
    load16(qkv + (size_t)(bS + kvb + row) * N3_ + 2048 + hoff + 8 * k8,
           lds + buf * 8192 + p * 16);
    load16(vt + (size_t)(bh64 + row) * S_ + kvb + 8 * k8,
           lds + 16384 + buf * 8192 + p * 16);
  }
}

__global__ __launch_bounds__(256, 3) void attn_kernel(const unsigned short* __restrict__ qkv,
                                                      const unsigned short* __restrict__ vt,
                                                      unsigned short* __restrict__ ao) {
  __shared__ __align__(16) unsigned char lds[49152];
  const int tid = threadIdx.x;
  const int lane = tid & 63, wv = tid >> 6;
  const int g = lane >> 4, l16 = lane & 15;
  // LPT order (big qi first) + XCD grouping on bh
  const int bid = blockIdx.x;
  const int qi = 15 - (bid >> 6);
  const int t6 = bid & 63;
  const int bh = ((t6 & 7) << 3) | (t6 >> 3);
  const int b = bh >> 5, h = bh & 31;
  const int qbase = qi * 128;
  const int srow0 = qbase + wv * 32;
  const int bS = b * S_, bh64 = bh * 64, hoff = h * 64;

  // Q fragments (B-operand: lane l16 = q-row, holds d = kt*32 + g*8 .. +7)
  bf16x8 qf[2][2];
#pragma unroll
  for (int m = 0; m < 2; ++m)
#pragma unroll
    for (int kt = 0; kt < 2; ++kt)
      qf[m][kt] = *(const bf16x8*)(qkv + (size_t)(bS + srow0 + m * 16 + l16) * N3_ +
                                   hoff + kt * 32 + g * 8);

  float mrun[2] = {-INFINITY, -INFINITY}, lrun[2] = {0.f, 0.f};
  f32x4 o[2][4] = {};
  unsigned char* pw = lds + 32768 + wv * 4096;  // 32 rows x 64k bf16

  const int nkv = (qbase + 128) >> 6;
  stage_kv(qkv, vt, lds, bS, bh64, hoff, 0, 0, tid);
  __syncthreads();

  for (int kb = 0; kb < nkv; ++kb) {
    const int cur = kb & 1;
    if (kb + 1 < nkv) stage_kv(qkv, vt, lds, bS, bh64, hoff, (kb + 1) << 6, cur ^ 1, tid);
    const int kvb = kb << 6;
    if (kvb <= srow0 + 31) {
      const unsigned char* kbuf = lds + cur * 8192;
      const unsigned char* vbuf = lds + 16384 + cur * 8192;

      // ---- QK^T (swapped): sc[m][n][r] = S[q = srow0+m*16+l16][k = kvb+n*16+g*4+r]
      f32x4 sc[2][4];
#pragma unroll
      for (int n = 0; n < 4; ++n) {
        int row = n * 16 + l16;
        bf16x8 kf0 = *(const bf16x8*)(kbuf + (row * 8 + ((g + 0) ^ (row & 7))) * 16);
        bf16x8 kf1 = *(const bf16x8*)(kbuf + (row * 8 + ((g + 4) ^ (row & 7))) * 16);
#pragma unroll
        for (int m = 0; m < 2; ++m) {
          f32x4 z = {};
          z = mfma16(kf0, qf[m][0], z);
          z = mfma16(kf1, qf[m][1], z);
          sc[m][n] = z;
        }
      }

      const bool boundary = (kvb + 63 > srow0);
#pragma unroll
      for (int m = 0; m < 2; ++m) {
        const int qrow = srow0 + m * 16 + l16;
        if (boundary) {
#pragma unroll
          for (int n = 0; n < 4; ++n)
#pragma unroll
            for (int r = 0; r < 4; ++r) {
              int k = kvb + n * 16 + g * 4 + r;
              if (k > qrow) sc[m][n][r] = -INFINITY;
            }
        }
        // row max: 15 in-lane + 2 shfl
        float mx = fmaxf(fmaxf(sc[m][0][0], sc[m][0][1]), fmaxf(sc[m][0][2], sc[m][0][3]));
#pragma unroll
        for (int n = 1; n < 4; ++n)
          mx = fmaxf(mx, fmaxf(fmaxf(sc[m][n][0], sc[m][n][1]), fmaxf(sc[m][n][2], sc[m][n][3])));
        mx = fmaxf(mx, __shfl_xor(mx, 16));
        mx = fmaxf(mx, __shfl_xor(mx, 32));
        float pm = mx * 0.125f;  // scaled-score domain
        if (!__all(pm <= mrun[m] + 8.0f)) {  // T13 defer-max
          float mn = fmaxf(mrun[m], pm);
          float al = exp2f((mrun[m] - mn) * 1.44269504f);
          mrun[m] = mn; lrun[m] *= al;
#pragma unroll
          for (int d = 0; d < 4; ++d) o[m][d] *= al;
        }
        const float mt = mrun[m] * 1.44269504f;
        float p[4][4]; float rs = 0.f;
#pragma unroll
        for (int n = 0; n < 4; ++n)
#pragma unroll
          for (int r = 0; r < 4; ++r) {
            p[n][r] = exp2f(fmaf(sc[m][n][r], 0.18033688011112042f, -mt));
            rs += p[n][r];
          }
        rs += __shfl_xor(rs, 16);
        rs += __shfl_xor(rs, 32);
        lrun[m] += rs;
        // pack + swizzled LDS write (rows m*16+l16)
#pragma unroll
        for (int n = 0; n < 4; ++n) {
          unsigned lo, hi;
          asm("v_cvt_pk_bf16_f32 %0, %1, %2" : "=v"(lo) : "v"(p[n][0]), "v"(p[n][1]));
          asm("v_cvt_pk_bf16_f32 %0, %1, %2" : "=v"(hi) : "v"(p[n][2]), "v"(p[n][3]));
          int su = (n * 4 + g) ^ ((l16 & 7) << 1);
          u32x2 w; w[0] = lo; w[1] = hi;
          *(u32x2*)(pw + ((m * 16 + l16) * 16 + su) * 8) = w;
        }
      }

      // ---- read exchanged P (lane l16 = q-row, k = kt*32 + g*8 .. +7)
      bf16x8 pf[2][2];
#pragma unroll
      for (int m = 0; m < 2; ++m)
#pragma unroll
        for (int kt = 0; kt < 2; ++kt) {
          int su = (kt * 8 + g * 2) ^ ((l16 & 7) << 1);
          pf[m][kt] = *(const bf16x8*)(pw + ((m * 16 + l16) * 16 + su) * 8);
        }
      // ---- PV (swapped): o[m][dblk] = O^T fragment, q = l16, d = dblk*16+g*4+r
#pragma unroll
      for (int dblk = 0; dblk < 4; ++dblk) {
        int row = dblk * 16 + l16;
        bf16x8 vf0 = *(const bf16x8*)(vbuf + (row * 8 + ((g + 0) ^ (row & 7))) * 16);
        bf16x8 vf1 = *(const bf16x8*)(vbuf + (row * 8 + ((g + 4) ^ (row & 7))) * 16);
#pragma unroll
        for (int m = 0; m < 2; ++m) {
          o[m][dblk] = mfma16(vf0, pf[m][0], o[m][dblk]);
          o[m][dblk] = mfma16(vf1, pf[m][1], o[m][dblk]);
        }
      }
    }
    __syncthreads();
  }

#pragma unroll
  for (int m = 0; m < 2; ++m) {
    float inv = 1.0f / lrun[m];
    int q = srow0 + m * 16 + l16;
#pragma unroll
    for (int dblk = 0; dblk < 4; ++dblk) {
      u16x4 ov;
#pragma unroll
      for (int r = 0; r < 4; ++r) ov[r] = f2bf(o[m][dblk][r] * inv);
      *(u16x4*)(ao + (size_t)(bS + q) * D_ + hoff + dblk * 16 + g * 4) = ov;
    }
  }
}

// ---------------------------------------------------------------------- launch
extern "C" void kernel_launch(void* const* d_in, const int* in_sizes, int n_in,
                              void* d_out, int out_size, void* d_ws, size_t ws_size,
                              hipStream_t stream) {
  const float* x = (const float*)d_in[0];
  const float* Wqkv = (const float*)d_in[1];
  const float* bqkv = (const float*)d_in[2];
  const float* Wout = (const float*)d_in[3];
  const float* bout = (const float*)d_in[4];
  float* out = (float*)d_out;

  char* ws = (char*)d_ws;
  unsigned short* Xb = (unsigned short*)(ws + 0);                  // 16 MiB (reused as AO)
  unsigned short* Wqkvt = (unsigned short*)(ws + 16777216);        // 24 MiB
  unsigned short* Woutt = (unsigned short*)(ws + 41943040);        // 8 MiB
  unsigned short* QKVb = (unsigned short*)(ws + 50331648);         // 48 MiB
  unsigned short* Vt = (unsigned short*)(ws + 100663296);          // 16 MiB
  unsigned short* AO = Xb;  // Xb is dead after gemm1

  cvt_bf16<<<4096, 256, 0, stream>>>(x, Xb, M_ * D_);
  transpose_bf16<<<dim3(192, 64), 256, 0, stream>>>(Wqkv, Wqkvt, 2048, 6144);
  transpose_bf16<<<dim3(64, 64), 256, 0, stream>>>(Wout, Woutt, 2048, 2048);
  gemm_bt<1><<<dim3(32, 48), 256, 0, stream>>>(Xb, Wqkvt, bqkv, QKVb, M_, N3_, D_);
  rope_kernel<<<512, 256, 0, stream>>>(QKVb);
  vtrans<<<dim3(32, 64), 256, 0, stream>>>(QKVb, Vt);
  attn_kernel<<<1024, 256, 0, stream>>>(QKVb, Vt, AO);
  gemm_bt<0><<<dim3(32, 16), 256, 0, stream>>>(AO, Woutt, bout, out, M_, D_, D_);
}

// Round 3
// 298.736 us; speedup vs baseline: 1.5021x; 1.0271x over previous
//
#include <hip/hip_runtime.h>
#include <stdint.h>
#include <math.h>

#define DEV static __device__ __forceinline__

typedef __attribute__((ext_vector_type(8))) short bf16x8;
typedef __attribute__((ext_vector_type(4))) float f32x4;
typedef __attribute__((ext_vector_type(8))) unsigned short u16x8;
typedef __attribute__((ext_vector_type(4))) unsigned short u16x4;
typedef __attribute__((ext_vector_type(2))) unsigned int u32x2;

enum { B_ = 2, S_ = 2048, D_ = 2048, H_ = 32, HD_ = 64, N3_ = 6144, M_ = 4096 };

DEV unsigned short f2bf(float f) {
  unsigned u = __float_as_uint(f);
  u += 0x7FFFu + ((u >> 16) & 1u);
  return (unsigned short)(u >> 16);
}
DEV float bf2f(unsigned short s) { return __uint_as_float(((unsigned)s) << 16); }

DEV void load16(const void* g, void* l) {
  __builtin_amdgcn_global_load_lds((const __attribute__((address_space(1))) void*)g,
                                   (__attribute__((address_space(3))) void*)l,
                                   16, 0, 0);
}

DEV f32x4 mfma16(bf16x8 a, bf16x8 b, f32x4 c) {
  return __builtin_amdgcn_mfma_f32_16x16x32_bf16(a, b, c, 0, 0, 0);
}

// ---------------------------------------------------------------- cvt f32->bf16
__global__ __launch_bounds__(256) void cvt_bf16(const float* __restrict__ in,
                                                unsigned short* __restrict__ out, int n) {
  int i = blockIdx.x * 256 + threadIdx.x;
  if (i * 8 >= n) return;
  const float4* in4 = (const float4*)in;
  float4 a = in4[i * 2 + 0];
  float4 b = in4[i * 2 + 1];
  u16x8 o;
  o[0] = f2bf(a.x); o[1] = f2bf(a.y); o[2] = f2bf(a.z); o[3] = f2bf(a.w);
  o[4] = f2bf(b.x); o[5] = f2bf(b.y); o[6] = f2bf(b.z); o[7] = f2bf(b.w);
  *(u16x8*)(out + (size_t)i * 8) = o;
}

// ------------------------------------------- transpose f32 [K][N] -> bf16 [N][K]
__global__ __launch_bounds__(256) void transpose_bf16(const float* __restrict__ W,
                                                      unsigned short* __restrict__ Wt,
                                                      int Kg, int Ng) {
  __shared__ float tile[32][33];
  const int tn = blockIdx.x, tk = blockIdx.y;
  const int t = threadIdx.x;
  const int r = t >> 3, c4 = (t & 7) * 4;
  float4 v = *(const float4*)(W + (size_t)(tk * 32 + r) * Ng + tn * 32 + c4);
  tile[r][c4 + 0] = v.x; tile[r][c4 + 1] = v.y;
  tile[r][c4 + 2] = v.z; tile[r][c4 + 3] = v.w;
  __syncthreads();
  u16x4 o;
  o[0] = f2bf(tile[c4 + 0][r]);
  o[1] = f2bf(tile[c4 + 1][r]);
  o[2] = f2bf(tile[c4 + 2][r]);
  o[3] = f2bf(tile[c4 + 3][r]);
  *(u16x4*)(Wt + (size_t)(tn * 32 + r) * Kg + tk * 32 + c4) = o;
}

// ===================== 256x256 8-phase GEMM (C = A @ B^T + bias) ==============
// A: [Mg][Kg] bf16, BT: [Ng][Kg] bf16.  512 thr = 8 waves (2M x 4N).
// LDS 128KB: buf b at b*64KB: A 32KB | B 32KB.  Granule(r,u) = r*8 + (u^(r&7)).
// K-tile = 64 cols. 4 phases/K-tile, 16 MFMA each. vmcnt(6) once per K-tile.
template <int OUT_BF16>
__global__ __launch_bounds__(512, 2) void gemm256(const unsigned short* __restrict__ A,
                                                  const unsigned short* __restrict__ BT,
                                                  const float* __restrict__ bias,
                                                  void* __restrict__ Cout,
                                                  int Mg, int Ng, int Kg) {
  __shared__ __align__(16) char lds[131072];
  const int tid = threadIdx.x;
  const int lane = tid & 63, w = tid >> 6;
  const int g = (lane >> 4) & 3, l16 = lane & 15;
  const int wm = w >> 2, wn = w & 3;

  // XCD-bijective swizzle (gridDim.x % 8 == 0), tm fastest (Mg/256 == 16).
  const int wg = (blockIdx.x & 7) * (gridDim.x >> 3) + (blockIdx.x >> 3);
  const int tm = wg & 15, tn = wg >> 4;
  const int rb = tm * 256, cb = tn * 256;
  const int NT = Kg >> 6;

  // ---- ds_read offsets (bytes within A/B region)
  const int offA = (wm * 128 + l16) * 128;
  const int offB = (wn * 64 + l16) * 128;
  const int sux0 = ((0 + g) ^ (l16 & 7)) * 16;
  const int sux1 = ((4 + g) ^ (l16 & 7)) * 16;

  // ---- staging maps: half-tiles A0={0-63,128-191} A1={64-127,192-255}
  //                    B0={0-31,64-95,128-159,192-223} B1=complement
  const unsigned short* srcA[2][2];
  const unsigned short* srcB[2][2];
  int dstA[2][2], dstB[2][2];
#pragma unroll
  for (int j = 0; j < 2; ++j) {
    int lr0 = (j * 8 + w) * 8;
    int lr = lr0 + (lane >> 3);
    int su = lane & 7;
    int u = su ^ (lr & 7);
#pragma unroll
    for (int h = 0; h < 2; ++h) {
      int rA = lr + 64 * (h + (lr >> 6));
      int rA0 = lr0 + 64 * (h + (lr0 >> 6));
      int rB = ((lr >> 5) << 6) + h * 32 + (lr & 31);
      int rB0 = ((lr0 >> 5) << 6) + h * 32 + (lr0 & 31);
      srcA[h][j] = A + (size_t)(rb + rA) * Kg + u * 8;
      srcB[h][j] = BT + (size_t)(cb + rB) * Kg + u * 8;
      dstA[h][j] = rA0 * 128;
      dstB[h][j] = rB0 * 128;
    }
  }

#define STAGE_A(h, tgt) do { \
    char* _bs = (char*)lds + (((tgt)&1) << 16); \
    load16(srcA[h][0] + (size_t)(tgt) * 64, _bs + dstA[h][0]); \
    load16(srcA[h][1] + (size_t)(tgt) * 64, _bs + dstA[h][1]); } while (0)
#define STAGE_B(h, tgt) do { \
    char* _bs = (char*)lds + (((tgt)&1) << 16) + 32768; \
    load16(srcB[h][0] + (size_t)(tgt) * 64, _bs + dstB[h][0]); \
    load16(srcB[h][1] + (size_t)(tgt) * 64, _bs + dstB[h][1]); } while (0)

  // ---- prologue: tile0 complete + tile1 {A0,B0,B1}
  STAGE_A(0, 0); STAGE_B(0, 0); STAGE_B(1, 0); STAGE_A(1, 0);
  STAGE_A(0, 1); STAGE_B(0, 1); STAGE_B(1, 1);
  asm volatile("s_waitcnt vmcnt(6)" ::: "memory");
  __builtin_amdgcn_s_barrier();

  f32x4 acc[8][4] = {};
  bf16x8 a[4][2], b01[2][2], b23[2][2];

  for (int t = 0; t < NT; ++t) {
    const char* rA_ = (const char*)lds + ((t & 1) << 16);
    const char* rB_ = rA_ + 32768;
    // -------- P1: read A m0-3 (8) + B n0-1 (4); stage A1(t+1)
#pragma unroll
    for (int mf = 0; mf < 4; ++mf)
#pragma unroll
      for (int kh = 0; kh < 2; ++kh)
        a[mf][kh] = *(const bf16x8*)(rA_ + offA + mf * 2048 + (kh ? sux1 : sux0));
#pragma unroll
    for (int nf = 0; nf < 2; ++nf)
#pragma unroll
      for (int kh = 0; kh < 2; ++kh)
        b01[nf][kh] = *(const bf16x8*)(rB_ + offB + nf * 2048 + (kh ? sux1 : sux0));
    if (t + 1 < NT) STAGE_A(1, t + 1);
    asm volatile("s_waitcnt lgkmcnt(8)" ::: "memory");
    __builtin_amdgcn_s_barrier();
    asm volatile("s_waitcnt lgkmcnt(0)" ::: "memory");
    __builtin_amdgcn_s_setprio(1);
#pragma unroll
    for (int mf = 0; mf < 4; ++mf)
#pragma unroll
      for (int nf = 0; nf < 2; ++nf)
#pragma unroll
        for (int kh = 0; kh < 2; ++kh)
          acc[mf][nf] = mfma16(a[mf][kh], b01[nf][kh], acc[mf][nf]);
    __builtin_amdgcn_s_setprio(0);
    __builtin_amdgcn_s_barrier();
    // -------- P2: read B n2-3 (4); stage A0(t+2)
#pragma unroll
    for (int nf = 0; nf < 2; ++nf)
#pragma unroll
      for (int kh = 0; kh < 2; ++kh)
        b23[nf][kh] = *(const bf16x8*)(rB_ + offB + (nf + 2) * 2048 + (kh ? sux1 : sux0));
    if (t + 2 < NT) STAGE_A(0, t + 2);
    __builtin_amdgcn_s_barrier();
    asm volatile("s_waitcnt lgkmcnt(0)" ::: "memory");
    __builtin_amdgcn_s_setprio(1);
#pragma unroll
    for (int mf = 0; mf < 4; ++mf)
#pragma unroll
      for (int nf = 0; nf < 2; ++nf)
#pragma unroll
        for (int kh = 0; kh < 2; ++kh)
          acc[mf][nf + 2] = mfma16(a[mf][kh], b23[nf][kh], acc[mf][nf + 2]);
    __builtin_amdgcn_s_setprio(0);
    __builtin_amdgcn_s_barrier();
    // -------- P3: read A m4-7 (8); stage B0(t+2)
#pragma unroll
    for (int mf = 0; mf < 4; ++mf)
#pragma unroll
      for (int kh = 0; kh < 2; ++kh)
        a[mf][kh] = *(const bf16x8*)(rA_ + offA + (mf + 4) * 2048 + (kh ? sux1 : sux0));
    if (t + 2 < NT) STAGE_B(0, t + 2);
    __builtin_amdgcn_s_barrier();
    asm volatile("s_waitcnt lgkmcnt(0)" ::: "memory");
    __builtin_amdgcn_s_setprio(1);
#pragma unroll
    for (int mf = 0; mf < 4; ++mf)
#pragma unroll
      for (int nf = 0; nf < 2; ++nf)
#pragma unroll
        for (int kh = 0; kh < 2; ++kh)
          acc[mf + 4][nf] = mfma16(a[mf][kh], b01[nf][kh], acc[mf + 4][nf]);
    __builtin_amdgcn_s_setprio(0);
    __builtin_amdgcn_s_barrier();
    // -------- P4: stage B1(t+2); counted vmcnt (6 steady, 0 drain)
    if (t + 2 < NT) {
      STAGE_B(1, t + 2);
      asm volatile("s_waitcnt vmcnt(6)" ::: "memory");
    } else {
      asm volatile("s_waitcnt vmcnt(0)" ::: "memory");
    }
    __builtin_amdgcn_s_barrier();
    __builtin_amdgcn_s_setprio(1);
#pragma unroll
    for (int mf = 0; mf < 4; ++mf)
#pragma unroll
      for (int nf = 0; nf < 2; ++nf)
#pragma unroll
        for (int kh = 0; kh < 2; ++kh)
          acc[mf + 4][nf + 2] = mfma16(a[mf][kh], b23[nf][kh], acc[mf + 4][nf + 2]);
    __builtin_amdgcn_s_setprio(0);
    __builtin_amdgcn_s_barrier();
  }
#undef STAGE_A
#undef STAGE_B

  // ---- epilogue
  const int crow0 = rb + wm * 128 + g * 4;
  const int ccol0 = cb + wn * 64 + l16;
#pragma unroll
  for (int mf = 0; mf < 8; ++mf)
#pragma unroll
    for (int nf = 0; nf < 4; ++nf) {
      float bv = bias[ccol0 + nf * 16];
#pragma unroll
      for (int r = 0; r < 4; ++r) {
        int row = crow0 + mf * 16 + r;
        int col = ccol0 + nf * 16;
        float v = acc[mf][nf][r] + bv;
        if (OUT_BF16)
          ((unsigned short*)Cout)[(size_t)row * Ng + col] = f2bf(v);
        else
          ((float*)Cout)[(size_t)row * Ng + col] = v;
      }
    }
}

// -------------------------------------------------------------- RoPE (in place)
__global__ __launch_bounds__(256) void rope_kernel(unsigned short* __restrict__ qkv) {
  const int idx = blockIdx.x * 256 + threadIdx.x;  // (b, s, h)
  const int h = idx & 31;
  const int s = (idx >> 5) & (S_ - 1);
  const int b = idx >> 16;
  float cs[16], sn[16];
#pragma unroll
  for (int j = 0; j < 16; ++j) {
    float inv = exp2f(-(float)j * 0.83048202372184056f);  // log2(10000)/16
    float fr = (float)s * inv;
    sincosf(fr, &sn[j], &cs[j]);
  }
  size_t base = (size_t)(b * S_ + s) * N3_ + h * 64;
#pragma unroll
  for (int part = 0; part < 2; ++part) {  // q then k
    unsigned short* p = qkv + base + part * 2048;
    u16x8 u0 = *(u16x8*)(p + 0), u1 = *(u16x8*)(p + 8);
    u16x8 u2 = *(u16x8*)(p + 16), u3 = *(u16x8*)(p + 24);
    float a1[16], a2[16];
#pragma unroll
    for (int j = 0; j < 8; ++j) {
      a1[j] = bf2f(u0[j]); a1[j + 8] = bf2f(u1[j]);
      a2[j] = bf2f(u2[j]); a2[j + 8] = bf2f(u3[j]);
    }
    u16x8 r0, r1, r2, r3;
#pragma unroll
    for (int j = 0; j < 8; ++j) {
      r0[j] = f2bf(a1[j] * cs[j] - a2[j] * sn[j]);
      r2[j] = f2bf(a1[j] * sn[j] + a2[j] * cs[j]);
      r1[j] = f2bf(a1[j + 8] * cs[j + 8] - a2[j + 8] * sn[j + 8]);
      r3[j] = f2bf(a1[j + 8] * sn[j + 8] + a2[j + 8] * cs[j + 8]);
    }
    *(u16x8*)(p + 0) = r0;  *(u16x8*)(p + 8) = r1;
    *(u16x8*)(p + 16) = r2; *(u16x8*)(p + 24) = r3;
  }
}

// ------------------------------------------------- V transpose -> [B,H,64,S]
__global__ __launch_bounds__(256) void vtrans(const unsigned short* __restrict__ qkv,
                                              unsigned short* __restrict__ vt) {
  __shared__ unsigned short tile[64][72];
  const int s0 = blockIdx.x * 64;
  const int bh = blockIdx.y;
  const int b = bh >> 5, h = bh & 31;
  const int t = threadIdx.x;
#pragma unroll
  for (int c = 0; c < 2; ++c) {
    int sl = (c * 256 + t) >> 3, d8 = t & 7;
    u16x8 v = *(const u16x8*)(qkv + (size_t)(b * S_ + s0 + sl) * N3_ + 4096 + h * 64 + d8 * 8);
    *(u16x8*)(&tile[sl][d8 * 8]) = v;
  }
  __syncthreads();
#pragma unroll
  for (int c = 0; c < 2; ++c) {
    int dl = (c * 256 + t) >> 3, s8 = t & 7;
    u16x8 o;
#pragma unroll
    for (int j = 0; j < 8; ++j) o[j] = tile[s8 * 8 + j][dl];
    *(u16x8*)(vt + (size_t)(bh * 64 + dl) * S_ + s0 + s8 * 8) = o;
  }
}

// ----------------------------------------------------------- flash attention
DEV void stage_kv(const unsigned short* __restrict__ qkv,
                  const unsigned short* __restrict__ vt,
                  unsigned char* lds, int bS, int bh64, int hoff, int kvb, int buf, int tid) {
#pragma unroll
  for (int c = 0; c < 2; ++c) {
    int p = c * 256 + tid;
    int row = p >> 3, k8 = (p & 7) ^ (row & 7);
    load16(qkv + (size_t)(bS + kvb + row) * N3_ + 2048 + hoff + 8 * k8,
           lds + buf * 8192 + p * 16);
    load16(vt + (size_t)(bh64 + row) * S_ + kvb + 8 * k8,
           lds + 16384 + buf * 8192 + p * 16);
  }
}

__global__ __launch_bounds__(256, 3) void attn_kernel(const unsigned short* __restrict__ qkv,
                                                      const unsigned short* __restrict__ vt,
                                                      unsigned short* __restrict__ ao) {
  __shared__ __align__(16) unsigned char lds[49152];
  const int tid = threadIdx.x;
  const int lane = tid & 63, wv = tid >> 6;
  const int g = lane >> 4, l16 = lane & 15;
  const int bid = blockIdx.x;
  const int qi = 15 - (bid >> 6);
  const int t6 = bid & 63;
  const int bh = ((t6 & 7) << 3) | (t6 >> 3);
  const int b = bh >> 5, h = bh & 31;
  const int qbase = qi * 128;
  const int srow0 = qbase + wv * 32;
  const int bS = b * S_, bh64 = bh * 64, hoff = h * 64;

  bf16x8 qf[2][2];
#pragma unroll
  for (int m = 0; m < 2; ++m)
#pragma unroll
    for (int kt = 0; kt < 2; ++kt)
      qf[m][kt] = *(const bf16x8*)(qkv + (size_t)(bS + srow0 + m * 16 + l16) * N3_ +
                                   hoff + kt * 32 + g * 8);

  float mrun[2] = {-INFINITY, -INFINITY}, lrun[2] = {0.f, 0.f};
  f32x4 o[2][4] = {};
  unsigned char* pw = lds + 32768 + wv * 4096;

  const int nkv = (qbase + 128) >> 6;
  stage_kv(qkv, vt, lds, bS, bh64, hoff, 0, 0, tid);
  __syncthreads();

  for (int kb = 0; kb < nkv; ++kb) {
    const int cur = kb & 1;
    if (kb + 1 < nkv) stage_kv(qkv, vt, lds, bS, bh64, hoff, (kb + 1) << 6, cur ^ 1, tid);
    const int kvb = kb << 6;
    if (kvb <= srow0 + 31) {
      const unsigned char* kbuf = lds + cur * 8192;
      const unsigned char* vbuf = lds + 16384 + cur * 8192;

      f32x4 sc[2][4];
#pragma unroll
      for (int n = 0; n < 4; ++n) {
        int row = n * 16 + l16;
        bf16x8 kf0 = *(const bf16x8*)(kbuf + (row * 8 + ((g + 0) ^ (row & 7))) * 16);
        bf16x8 kf1 = *(const bf16x8*)(kbuf + (row * 8 + ((g + 4) ^ (row & 7))) * 16);
#pragma unroll
        for (int m = 0; m < 2; ++m) {
          f32x4 z = {};
          z = mfma16(kf0, qf[m][0], z);
          z = mfma16(kf1, qf[m][1], z);
          sc[m][n] = z;
        }
      }

      const bool boundary = (kvb + 63 > srow0);
#pragma unroll
      for (int m = 0; m < 2; ++m) {
        const int qrow = srow0 + m * 16 + l16;
        if (boundary) {
#pragma unroll
          for (int n = 0; n < 4; ++n)
#pragma unroll
            for (int r = 0; r < 4; ++r) {
              int k = kvb + n * 16 + g * 4 + r;
              if (k > qrow) sc[m][n][r] = -INFINITY;
            }
        }
        float mx = fmaxf(fmaxf(sc[m][0][0], sc[m][0][1]), fmaxf(sc[m][0][2], sc[m][0][3]));
#pragma unroll
        for (int n = 1; n < 4; ++n)
          mx = fmaxf(mx, fmaxf(fmaxf(sc[m][n][0], sc[m][n][1]), fmaxf(sc[m][n][2], sc[m][n][3])));
        mx = fmaxf(mx, __shfl_xor(mx, 16));
        mx = fmaxf(mx, __shfl_xor(mx, 32));
        float pm = mx * 0.125f;
        if (!__all(pm <= mrun[m] + 8.0f)) {
          float mn = fmaxf(mrun[m], pm);
          float al = exp2f((mrun[m] - mn) * 1.44269504f);
          mrun[m] = mn; lrun[m] *= al;
#pragma unroll
          for (int d = 0; d < 4; ++d) o[m][d] *= al;
        }
        const float mt = mrun[m] * 1.44269504f;
        float p[4][4]; float rs = 0.f;
#pragma unroll
        for (int n = 0; n < 4; ++n)
#pragma unroll
          for (int r = 0; r < 4; ++r) {
            p[n][r] = exp2f(fmaf(sc[m][n][r], 0.18033688011112042f, -mt));
            rs += p[n][r];
          }
        rs += __shfl_xor(rs, 16);
        rs += __shfl_xor(rs, 32);
        lrun[m] += rs;
#pragma unroll
        for (int n = 0; n < 4; ++n) {
          unsigned lo, hi;
          asm("v_cvt_pk_bf16_f32 %0, %1, %2" : "=v"(lo) : "v"(p[n][0]), "v"(p[n][1]));
          asm("v_cvt_pk_bf16_f32 %0, %1, %2" : "=v"(hi) : "v"(p[n][2]), "v"(p[n][3]));
          int su = (n * 4 + g) ^ ((l16 & 7) << 1);
          u32x2 wq; wq[0] = lo; wq[1] = hi;
          *(u32x2*)(pw + ((m * 16 + l16) * 16 + su) * 8) = wq;
        }
      }

      bf16x8 pf[2][2];
#pragma unroll
      for (int m = 0; m < 2; ++m)
#pragma unroll
        for (int kt = 0; kt < 2; ++kt) {
          int su = (kt * 8 + g * 2) ^ ((l16 & 7) << 1);
          pf[m][kt] = *(const bf16x8*)(pw + ((m * 16 + l16) * 16 + su) * 8);
        }
#pragma unroll
      for (int dblk = 0; dblk < 4; ++dblk) {
        int row = dblk * 16 + l16;
        bf16x8 vf0 = *(const bf16x8*)(vbuf + (row * 8 + ((g + 0) ^ (row & 7))) * 16);
        bf16x8 vf1 = *(const bf16x8*)(vbuf + (row * 8 + ((g + 4) ^ (row & 7))) * 16);
#pragma unroll
        for (int m = 0; m < 2; ++m) {
          o[m][dblk] = mfma16(vf0, pf[m][0], o[m][dblk]);
          o[m][dblk] = mfma16(vf1, pf[m][1], o[m][dblk]);
        }
      }
    }
    __syncthreads();
  }

#pragma unroll
  for (int m = 0; m < 2; ++m) {
    float inv = 1.0f / lrun[m];
    int q = srow0 + m * 16 + l16;
#pragma unroll
    for (int dblk = 0; dblk < 4; ++dblk) {
      u16x4 ov;
#pragma unroll
      for (int r = 0; r < 4; ++r) ov[r] = f2bf(o[m][dblk][r] * inv);
      *(u16x4*)(ao + (size_t)(bS + q) * D_ + hoff + dblk * 16 + g * 4) = ov;
    }
  }
}

// ---------------------------------------------------------------------- launch
extern "C" void kernel_launch(void* const* d_in, const int* in_sizes, int n_in,
                              void* d_out, int out_size, void* d_ws, size_t ws_size,
                              hipStream_t stream) {
  const float* x = (const float*)d_in[0];
  const float* Wqkv = (const float*)d_in[1];
  const float* bqkv = (const float*)d_in[2];
  const float* Wout = (const float*)d_in[3];
  const float* bout = (const float*)d_in[4];
  float* out = (float*)d_out;

  char* ws = (char*)d_ws;
  unsigned short* Xb = (unsigned short*)(ws + 0);                  // 16 MiB (reused as AO)
  unsigned short* Wqkvt = (unsigned short*)(ws + 16777216);        // 24 MiB
  unsigned short* Woutt = (unsigned short*)(ws + 41943040);        // 8 MiB
  unsigned short* QKVb = (unsigned short*)(ws + 50331648);         // 48 MiB
  unsigned short* Vt = (unsigned short*)(ws + 100663296);          // 16 MiB
  unsigned short* AO = Xb;  // Xb is dead after gemm1

  cvt_bf16<<<4096, 256, 0, stream>>>(x, Xb, M_ * D_);
  transpose_bf16<<<dim3(192, 64), 256, 0, stream>>>(Wqkv, Wqkvt, 2048, 6144);
  transpose_bf16<<<dim3(64, 64), 256, 0, stream>>>(Wout, Woutt, 2048, 2048);
  gemm256<1><<<384, 512, 0, stream>>>(Xb, Wqkvt, bqkv, QKVb, M_, N3_, D_);
  rope_kernel<<<512, 256, 0, stream>>>(QKVb);
  vtrans<<<dim3(32, 64), 256, 0, stream>>>(QKVb, Vt);
  attn_kernel<<<1024, 256, 0, stream>>>(QKVb, Vt, AO);
  gemm256<0><<<128, 512, 0, stream>>>(AO, Woutt, bout, out, M_, D_, D_);
}